// Round 2
// baseline (291.469 us; speedup 1.0000x reference)
//
#include <hip/hip_runtime.h>

#define DEV static __device__ __forceinline__

typedef __attribute__((ext_vector_type(8))) short short8;
typedef __attribute__((ext_vector_type(4))) float f32x4;

DEV unsigned short f2bf(float f) {
    union { float f; unsigned int u; } v; v.f = f;
    unsigned int u = v.u;
    unsigned int r = (u + 0x7fffu + ((u >> 16) & 1u)) >> 16;
    return (unsigned short)r;
}

// XOR-swizzled LDS pointer: tile row stride rs shorts (power of 2), byte ^= (row&7)<<4
DEV unsigned short* swp(unsigned short* base, int row, int col, int rs) {
    int a = ((row * rs + col) << 1) ^ ((row & 7) << 4);
    return (unsigned short*)((char*)base + a);
}

// ---------------- kernel 0: fp32 weights -> bf16 ----------------
__global__ void prep_kernel(const float* __restrict__ qkv_w,
                            const float* __restrict__ proj_w,
                            unsigned short* __restrict__ Wq,
                            unsigned short* __restrict__ Wp) {
    int i = blockIdx.x * blockDim.x + threadIdx.x;
    int stride = gridDim.x * blockDim.x;
    for (int j = i; j < 1536 * 512; j += stride) Wq[j] = f2bf(qkv_w[j]);
    for (int j = i; j < 512 * 512;  j += stride) Wp[j] = f2bf(proj_w[j]);
}

// ---------------- kernel 1: x [b][512][2048] f32 -> Xt [b][2048][512] bf16
__global__ __launch_bounds__(256) void transpose_kernel(const float* __restrict__ x,
                                                        unsigned short* __restrict__ Xt) {
    __shared__ unsigned char lt[64 * 128];  // 64 c-rows x 64 t bf16, XOR-swizzled
    int b  = blockIdx.z;
    int c0 = blockIdx.y * 64;
    int t0 = blockIdx.x * 64;
    int tid = threadIdx.x;
    // phase 1: coalesced float4 reads along t, b64 swizzled LDS writes
    int tx = tid & 15, cy0 = tid >> 4;
    for (int p = 0; p < 4; ++p) {
        int cy = cy0 + p * 16;
        const float* src = &x[((size_t)(b * 512 + c0 + cy)) * 2048 + t0 + tx * 4];
        f32x4 v = *(const f32x4*)src;
        unsigned long long pk = (unsigned long long)f2bf(v[0])
                              | ((unsigned long long)f2bf(v[1]) << 16)
                              | ((unsigned long long)f2bf(v[2]) << 32)
                              | ((unsigned long long)f2bf(v[3]) << 48);
        int addr = (cy * 128 + tx * 8) ^ ((cy & 7) << 4);
        *(unsigned long long*)(lt + addr) = pk;
    }
    __syncthreads();
    // phase 2: gather 16 c per thread, 32B coalesced global writes
    int c16 = (tid & 3) * 16, tr = tid >> 2;
    unsigned short buf[16];
    for (int i = 0; i < 16; ++i) {
        int c = c16 + i;
        int addr = (c * 128 + tr * 2) ^ ((c & 7) << 4);
        buf[i] = *(unsigned short*)(lt + addr);
    }
    unsigned short* dst = &Xt[((size_t)(b * 2048 + t0 + tr)) * 512 + c0 + c16];
    *(short8*)dst       = *(short8*)&buf[0];
    *(short8*)(dst + 8) = *(short8*)&buf[8];
}

// ---------------- kernel 2: QKV GEMM ----------------
// ORIENT 0: D[t][o] (Q/K tiles, o-tile 0..7)  -> Qw/Kw [bh][T][ch]
// ORIENT 1: D[o][t] (V tiles,  o-tile 8..11)  -> Vw    [bh][ch][T]
#define LP 72  // 64 + 8 pad (keeps ds_read_b128 16B-aligned, ~2-way banks)

template <int ORIENT>
__global__ __launch_bounds__(256, 2) void gemm_qkv_kernel(
    const unsigned short* __restrict__ Wq,   // [1536][512] bf16
    const unsigned short* __restrict__ Xt,   // [b][2048][512] bf16
    const float* __restrict__ qkv_b,
    unsigned short* __restrict__ Qw,
    unsigned short* __restrict__ Kw,
    unsigned short* __restrict__ Vw) {
    __shared__ unsigned short Ws[128][LP];   // [o][k]
    __shared__ unsigned short Bs[128][LP];   // [t][k]
    int b  = blockIdx.z;
    int ot = (ORIENT == 0) ? blockIdx.y : (8 + blockIdx.y);
    int o0 = ot * 128, t0 = blockIdx.x * 128;
    int tid = threadIdx.x, lane = tid & 63, w = tid >> 6;
    int lr = lane >> 4, lc = lane & 15;
    int wr = (w >> 1) * 64, wc = (w & 1) * 64;
    f32x4 acc[4][4];
    for (int m = 0; m < 4; m++)
        for (int n = 0; n < 4; n++) acc[m][n] = (f32x4){0.f, 0.f, 0.f, 0.f};
    int srow = tid >> 3, soff = (tid & 7) * 8;
    for (int k0 = 0; k0 < 512; k0 += 64) {
        __syncthreads();
        for (int rr = srow; rr < 128; rr += 32) {
            *(short8*)&Ws[rr][soff] = *(const short8*)&Wq[(size_t)(o0 + rr) * 512 + k0 + soff];
            *(short8*)&Bs[rr][soff] = *(const short8*)&Xt[((size_t)(b * 2048) + t0 + rr) * 512 + k0 + soff];
        }
        __syncthreads();
        for (int kk = 0; kk < 64; kk += 32) {
            int kb = kk + lr * 8;
            short8 af[4], bfv[4];
            if (ORIENT == 0) {
                for (int m = 0; m < 4; m++) af[m]  = *(const short8*)&Bs[wr + m * 16 + lc][kb];
                for (int n = 0; n < 4; n++) bfv[n] = *(const short8*)&Ws[wc + n * 16 + lc][kb];
            } else {
                for (int m = 0; m < 4; m++) af[m]  = *(const short8*)&Ws[wr + m * 16 + lc][kb];
                for (int n = 0; n < 4; n++) bfv[n] = *(const short8*)&Bs[wc + n * 16 + lc][kb];
            }
            for (int m = 0; m < 4; m++)
                for (int n = 0; n < 4; n++)
                    acc[m][n] = __builtin_amdgcn_mfma_f32_16x16x32_bf16(af[m], bfv[n], acc[m][n], 0, 0, 0);
        }
    }
    const float scale = 0.29730177875068026f;  // 128^-0.25
    for (int m = 0; m < 4; m++)
        for (int n = 0; n < 4; n++)
            for (int r = 0; r < 4; r++) {
                int row = wr + m * 16 + lr * 4 + r;
                int col = wc + n * 16 + lc;
                float val = acc[m][n][r];
                if (ORIENT == 0) {
                    int t = t0 + row;
                    int o = o0 + col;
                    val = (val + qkv_b[o]) * scale;
                    if (o < 512) {
                        int h = o >> 7, cc = o & 127;
                        Qw[((size_t)((b * 4 + h) * 2048 + t)) * 128 + cc] = f2bf(val);
                    } else {
                        int oo = o - 512;
                        int h = oo >> 7, cc = oo & 127;
                        Kw[((size_t)((b * 4 + h) * 2048 + t)) * 128 + cc] = f2bf(val);
                    }
                } else {
                    int o = o0 + row;
                    int t = t0 + col;
                    val += qkv_b[o];
                    int oo = o - 1024;
                    int h = oo >> 7, cc = oo & 127;
                    Vw[((size_t)((b * 4 + h) * 128 + cc)) * 2048 + t] = f2bf(val);
                }
            }
}

// ---------------- kernel 3: flash attention v2 ----------------
// block: 512 threads (8 waves), 128 q-rows; 16 q-rows/wave; KV tiles of 64
// LDS XOR-swizzled, 48KB -> 2 blocks/CU = 16 waves/CU
__global__ __launch_bounds__(512, 4) void attn_kernel(
    const unsigned short* __restrict__ Qw,   // [bh][2048][128]
    const unsigned short* __restrict__ Kw,   // [bh][2048][128]
    const unsigned short* __restrict__ Vw,   // [bh][128][2048]
    unsigned short* __restrict__ Aw) {       // [b][2048][512]
    __shared__ unsigned short Ks[64 * 128];  // [s][ch], swizzled
    __shared__ unsigned short Vs[128 * 64];  // [c][s],  swizzled
    __shared__ unsigned short Ps[128 * 64];  // [q][s],  swizzled
    int bh = blockIdx.y;
    int t0 = blockIdx.x * 128;
    int tid = threadIdx.x, lane = tid & 63, w = tid >> 6;
    int lr = lane >> 4, lc = lane & 15;
    int qrow = w * 16;

    // Q fragments resident: row qrow+lc, k = kk*32 + lr*8
    short8 qf[4];
    for (int kk = 0; kk < 4; kk++)
        qf[kk] = *(const short8*)&Qw[((size_t)bh * 2048 + t0 + qrow + lc) * 128 + kk * 32 + lr * 8];

    f32x4 oacc[8];
    for (int n = 0; n < 8; n++) oacc[n] = (f32x4){0.f, 0.f, 0.f, 0.f};
    float mst[4], lst[4];
    for (int r = 0; r < 4; r++) { mst[r] = -1e30f; lst[r] = 0.f; }

    int kr = tid >> 4, ko = (tid & 15) * 8;
    int vr = tid >> 3, vo = (tid & 7) * 8;

    for (int s0 = 0; s0 < 2048; s0 += 64) {
        __syncthreads();
        // stage K [64][128] and V [128][64], swizzled (2 passes each at 512 thr)
        for (int p = 0; p < 2; p++) {
            int rr = kr + p * 32;
            *(short8*)swp(Ks, rr, ko, 128) =
                *(const short8*)&Kw[((size_t)bh * 2048 + s0 + rr) * 128 + ko];
        }
        for (int p = 0; p < 2; p++) {
            int rr = vr + p * 64;
            *(short8*)swp(Vs, rr, vo, 64) =
                *(const short8*)&Vw[((size_t)bh * 128 + rr) * 2048 + s0 + vo];
        }
        __syncthreads();
        // S = Q K^T
        f32x4 sacc[4];
        for (int n = 0; n < 4; n++) sacc[n] = (f32x4){0.f, 0.f, 0.f, 0.f};
        __builtin_amdgcn_s_setprio(1);
        for (int kk = 0; kk < 4; kk++) {
            short8 kf[4];
            for (int n = 0; n < 4; n++)
                kf[n] = *(const short8*)swp(Ks, n * 16 + lc, kk * 32 + lr * 8, 128);
            for (int n = 0; n < 4; n++)
                sacc[n] = __builtin_amdgcn_mfma_f32_16x16x32_bf16(qf[kk], kf[n], sacc[n], 0, 0, 0);
        }
        __builtin_amdgcn_s_setprio(0);
        // online softmax (rows lr*4+r), wave-parallel over 16-lane groups
        for (int r = 0; r < 4; r++) {
            float mx = fmaxf(fmaxf(sacc[0][r], sacc[1][r]), fmaxf(sacc[2][r], sacc[3][r]));
            for (int d = 1; d < 16; d <<= 1) mx = fmaxf(mx, __shfl_xor(mx, d, 64));
            float mnew = fmaxf(mst[r], mx);
            float resc = __expf(mst[r] - mnew);
            mst[r] = mnew;
            float rs = 0.f;
            for (int n = 0; n < 4; n++) {
                float p0 = __expf(sacc[n][r] - mnew);
                sacc[n][r] = p0;
                rs += p0;
            }
            for (int d = 1; d < 16; d <<= 1) rs += __shfl_xor(rs, d, 64);
            lst[r] = lst[r] * resc + rs;
            for (int n = 0; n < 8; n++) oacc[n][r] *= resc;
        }
        // P -> LDS (bf16), wave-private rows, swizzled (2-way banks)
        for (int n = 0; n < 4; n++)
            for (int r = 0; r < 4; r++)
                *swp(Ps, qrow + lr * 4 + r, n * 16 + lc, 64) = f2bf(sacc[n][r]);
        asm volatile("" ::: "memory");
        // O += P V^T
        __builtin_amdgcn_s_setprio(1);
        for (int kk = 0; kk < 2; kk++) {
            short8 pa = *(const short8*)swp(Ps, qrow + lc, kk * 32 + lr * 8, 64);
            short8 vb[8];
            for (int n = 0; n < 8; n++)
                vb[n] = *(const short8*)swp(Vs, n * 16 + lc, kk * 32 + lr * 8, 64);
            for (int n = 0; n < 8; n++)
                oacc[n] = __builtin_amdgcn_mfma_f32_16x16x32_bf16(pa, vb[n], oacc[n], 0, 0, 0);
        }
        __builtin_amdgcn_s_setprio(0);
    }
    // epilogue: O / l -> Aw[b][t][h*128+c]
    int b = bh >> 2, h = bh & 3;
    float inv[4];
    for (int r = 0; r < 4; r++) inv[r] = 1.f / lst[r];
    for (int n = 0; n < 8; n++)
        for (int r = 0; r < 4; r++) {
            int t = t0 + qrow + lr * 4 + r;
            int c = h * 128 + n * 16 + lc;
            Aw[((size_t)(b * 2048) + t) * 512 + c] = f2bf(oacc[n][r] * inv[r]);
        }
}

// ---------------- kernel 4: proj GEMM + bias + residual ----------------
__global__ __launch_bounds__(256, 2) void gemm_proj_kernel(
    const unsigned short* __restrict__ Wp,   // [512][512] bf16
    const unsigned short* __restrict__ Aw,   // [b][2048][512] bf16
    const float* __restrict__ proj_b,
    const float* __restrict__ x,             // [b][512][2048] f32
    float* __restrict__ out) {
    __shared__ unsigned short Ws[128][LP];   // [o][k]
    __shared__ unsigned short Bs[128][LP];   // [t][k]
    int b  = blockIdx.z;
    int o0 = blockIdx.y * 128, t0 = blockIdx.x * 128;
    int tid = threadIdx.x, lane = tid & 63, w = tid >> 6;
    int lr = lane >> 4, lc = lane & 15;
    int wr = (w >> 1) * 64, wc = (w & 1) * 64;
    f32x4 acc[4][4];
    for (int m = 0; m < 4; m++)
        for (int n = 0; n < 4; n++) acc[m][n] = (f32x4){0.f, 0.f, 0.f, 0.f};
    int srow = tid >> 3, soff = (tid & 7) * 8;
    for (int k0 = 0; k0 < 512; k0 += 64) {
        __syncthreads();
        for (int rr = srow; rr < 128; rr += 32) {
            *(short8*)&Ws[rr][soff] = *(const short8*)&Wp[(size_t)(o0 + rr) * 512 + k0 + soff];
            *(short8*)&Bs[rr][soff] = *(const short8*)&Aw[((size_t)(b * 2048) + t0 + rr) * 512 + k0 + soff];
        }
        __syncthreads();
        for (int kk = 0; kk < 64; kk += 32) {
            int kb = kk + lr * 8;
            short8 af[4], bfv[4];
            for (int m = 0; m < 4; m++) af[m]  = *(const short8*)&Ws[wr + m * 16 + lc][kb];
            for (int n = 0; n < 4; n++) bfv[n] = *(const short8*)&Bs[wc + n * 16 + lc][kb];
            for (int m = 0; m < 4; m++)
                for (int n = 0; n < 4; n++)
                    acc[m][n] = __builtin_amdgcn_mfma_f32_16x16x32_bf16(af[m], bfv[n], acc[m][n], 0, 0, 0);
        }
    }
    // D[m=o][n=t]; out = x + h + bias (residual in fp32, exact)
    for (int m = 0; m < 4; m++)
        for (int n = 0; n < 4; n++)
            for (int r = 0; r < 4; r++) {
                int o = o0 + wr + m * 16 + lr * 4 + r;
                int t = t0 + wc + n * 16 + lc;
                size_t idx = ((size_t)(b * 512) + o) * 2048 + t;
                out[idx] = x[idx] + acc[m][n][r] + proj_b[o];
            }
}

extern "C" void kernel_launch(void* const* d_in, const int* in_sizes, int n_in,
                              void* d_out, int out_size, void* d_ws, size_t ws_size,
                              hipStream_t stream) {
    const float* x      = (const float*)d_in[0];
    const float* qkv_w  = (const float*)d_in[1];
    const float* qkv_b  = (const float*)d_in[2];
    const float* proj_w = (const float*)d_in[3];
    const float* proj_b = (const float*)d_in[4];
    float* out = (float*)d_out;

    unsigned short* ws = (unsigned short*)d_ws;
    unsigned short* Wq = ws;                                   // 1536*512
    unsigned short* Wp = Wq + (size_t)1536 * 512;              // 512*512
    unsigned short* Xt = Wp + (size_t)512 * 512;               // 8*2048*512
    unsigned short* Qw = Xt + (size_t)8 * 2048 * 512;          // 32*2048*128
    unsigned short* Kw = Qw + (size_t)32 * 2048 * 128;
    unsigned short* Vw = Kw + (size_t)32 * 2048 * 128;
    unsigned short* Aw = Vw + (size_t)32 * 2048 * 128;         // 8*2048*512

    prep_kernel<<<dim3(512), dim3(256), 0, stream>>>(qkv_w, proj_w, Wq, Wp);
    transpose_kernel<<<dim3(32, 8, 8), dim3(256), 0, stream>>>(x, Xt);
    gemm_qkv_kernel<0><<<dim3(16, 8, 8), dim3(256), 0, stream>>>(Wq, Xt, qkv_b, Qw, Kw, Vw);
    gemm_qkv_kernel<1><<<dim3(16, 4, 8), dim3(256), 0, stream>>>(Wq, Xt, qkv_b, Qw, Kw, Vw);
    attn_kernel<<<dim3(16, 32), dim3(512), 0, stream>>>(Qw, Kw, Vw, Aw);
    gemm_proj_kernel<<<dim3(16, 4, 8), dim3(256), 0, stream>>>(Wp, Aw, proj_b, x, out);
}

// Round 3
// 285.441 us; speedup vs baseline: 1.0211x; 1.0211x over previous
//
#include <hip/hip_runtime.h>

#define DEV static __device__ __forceinline__

typedef __attribute__((ext_vector_type(8))) short short8;
typedef __attribute__((ext_vector_type(4))) float f32x4;

DEV unsigned short f2bf(float f) {
    union { float f; unsigned int u; } v; v.f = f;
    unsigned int u = v.u;
    unsigned int r = (u + 0x7fffu + ((u >> 16) & 1u)) >> 16;
    return (unsigned short)r;
}

// XOR-swizzled LDS pointer: tile row stride rs shorts (power of 2), byte ^= (row&7)<<4
DEV unsigned short* swp(unsigned short* base, int row, int col, int rs) {
    int a = ((row * rs + col) << 1) ^ ((row & 7) << 4);
    return (unsigned short*)((char*)base + a);
}

// ---------------- kernel 0: fp32 weights -> bf16 ----------------
__global__ void prep_kernel(const float* __restrict__ qkv_w,
                            const float* __restrict__ proj_w,
                            unsigned short* __restrict__ Wq,
                            unsigned short* __restrict__ Wp) {
    int i = blockIdx.x * blockDim.x + threadIdx.x;
    int stride = gridDim.x * blockDim.x;
    for (int j = i; j < 1536 * 512; j += stride) Wq[j] = f2bf(qkv_w[j]);
    for (int j = i; j < 512 * 512;  j += stride) Wp[j] = f2bf(proj_w[j]);
}

// ---------------- kernel 1: x [b][512][2048] f32 -> Xt [b][2048][512] bf16
__global__ __launch_bounds__(256) void transpose_kernel(const float* __restrict__ x,
                                                        unsigned short* __restrict__ Xt) {
    __shared__ unsigned char lt[64 * 128];  // 64 c-rows x 64 t bf16, XOR-swizzled
    int b  = blockIdx.z;
    int c0 = blockIdx.y * 64;
    int t0 = blockIdx.x * 64;
    int tid = threadIdx.x;
    // phase 1: coalesced float4 reads along t, b64 swizzled LDS writes
    int tx = tid & 15, cy0 = tid >> 4;
    for (int p = 0; p < 4; ++p) {
        int cy = cy0 + p * 16;
        const float* src = &x[((size_t)(b * 512 + c0 + cy)) * 2048 + t0 + tx * 4];
        f32x4 v = *(const f32x4*)src;
        unsigned long long pk = (unsigned long long)f2bf(v[0])
                              | ((unsigned long long)f2bf(v[1]) << 16)
                              | ((unsigned long long)f2bf(v[2]) << 32)
                              | ((unsigned long long)f2bf(v[3]) << 48);
        int addr = (cy * 128 + tx * 8) ^ ((cy & 7) << 4);
        *(unsigned long long*)(lt + addr) = pk;
    }
    __syncthreads();
    // phase 2: gather 16 c per thread, 32B coalesced global writes
    int c16 = (tid & 3) * 16, tr = tid >> 2;
    unsigned short buf[16];
    for (int i = 0; i < 16; ++i) {
        int c = c16 + i;
        int addr = (c * 128 + tr * 2) ^ ((c & 7) << 4);
        buf[i] = *(unsigned short*)(lt + addr);
    }
    unsigned short* dst = &Xt[((size_t)(b * 2048 + t0 + tr)) * 512 + c0 + c16];
    *(short8*)dst       = *(short8*)&buf[0];
    *(short8*)(dst + 8) = *(short8*)&buf[8];
}

// ---------------- kernel 2: QKV GEMM ----------------
// ORIENT 0: D[t][o] (Q/K tiles, o-tile 0..7)  -> Qw/Kw [bh][T][ch]
// ORIENT 1: D[o][t] (V tiles,  o-tile 8..11)  -> Vw    [bh][ch][T]
#define LP 72  // 64 + 8 pad (keeps ds_read_b128 16B-aligned, ~2-way banks)

template <int ORIENT>
__global__ __launch_bounds__(256, 2) void gemm_qkv_kernel(
    const unsigned short* __restrict__ Wq,   // [1536][512] bf16
    const unsigned short* __restrict__ Xt,   // [b][2048][512] bf16
    const float* __restrict__ qkv_b,
    unsigned short* __restrict__ Qw,
    unsigned short* __restrict__ Kw,
    unsigned short* __restrict__ Vw) {
    __shared__ unsigned short Ws[128][LP];   // [o][k]
    __shared__ unsigned short Bs[128][LP];   // [t][k]
    int b  = blockIdx.z;
    int ot = (ORIENT == 0) ? blockIdx.y : (8 + blockIdx.y);
    int o0 = ot * 128, t0 = blockIdx.x * 128;
    int tid = threadIdx.x, lane = tid & 63, w = tid >> 6;
    int lr = lane >> 4, lc = lane & 15;
    int wr = (w >> 1) * 64, wc = (w & 1) * 64;
    f32x4 acc[4][4];
    for (int m = 0; m < 4; m++)
        for (int n = 0; n < 4; n++) acc[m][n] = (f32x4){0.f, 0.f, 0.f, 0.f};
    int srow = tid >> 3, soff = (tid & 7) * 8;
    for (int k0 = 0; k0 < 512; k0 += 64) {
        __syncthreads();
        for (int rr = srow; rr < 128; rr += 32) {
            *(short8*)&Ws[rr][soff] = *(const short8*)&Wq[(size_t)(o0 + rr) * 512 + k0 + soff];
            *(short8*)&Bs[rr][soff] = *(const short8*)&Xt[((size_t)(b * 2048) + t0 + rr) * 512 + k0 + soff];
        }
        __syncthreads();
        for (int kk = 0; kk < 64; kk += 32) {
            int kb = kk + lr * 8;
            short8 af[4], bfv[4];
            if (ORIENT == 0) {
                for (int m = 0; m < 4; m++) af[m]  = *(const short8*)&Bs[wr + m * 16 + lc][kb];
                for (int n = 0; n < 4; n++) bfv[n] = *(const short8*)&Ws[wc + n * 16 + lc][kb];
            } else {
                for (int m = 0; m < 4; m++) af[m]  = *(const short8*)&Ws[wr + m * 16 + lc][kb];
                for (int n = 0; n < 4; n++) bfv[n] = *(const short8*)&Bs[wc + n * 16 + lc][kb];
            }
            for (int m = 0; m < 4; m++)
                for (int n = 0; n < 4; n++)
                    acc[m][n] = __builtin_amdgcn_mfma_f32_16x16x32_bf16(af[m], bfv[n], acc[m][n], 0, 0, 0);
        }
    }
    const float scale = 0.29730177875068026f;  // 128^-0.25
    for (int m = 0; m < 4; m++)
        for (int n = 0; n < 4; n++)
            for (int r = 0; r < 4; r++) {
                int row = wr + m * 16 + lr * 4 + r;
                int col = wc + n * 16 + lc;
                float val = acc[m][n][r];
                if (ORIENT == 0) {
                    int t = t0 + row;
                    int o = o0 + col;
                    val = (val + qkv_b[o]) * scale;
                    if (o < 512) {
                        int h = o >> 7, cc = o & 127;
                        Qw[((size_t)((b * 4 + h) * 2048 + t)) * 128 + cc] = f2bf(val);
                    } else {
                        int oo = o - 512;
                        int h = oo >> 7, cc = oo & 127;
                        Kw[((size_t)((b * 4 + h) * 2048 + t)) * 128 + cc] = f2bf(val);
                    }
                } else {
                    int o = o0 + row;
                    int t = t0 + col;
                    val += qkv_b[o];
                    int oo = o - 1024;
                    int h = oo >> 7, cc = oo & 127;
                    Vw[((size_t)((b * 4 + h) * 128 + cc)) * 2048 + t] = f2bf(val);
                }
            }
}

// ---------------- kernel 3: flash attention v3 ----------------
// 256 threads = 4 waves x 32 q-rows = 128 q-rows/block; KV tiles of 64.
// Double-buffered K/V LDS with 1-tile register prefetch; ONE barrier per tile.
// LDS = 2*16 + 2*16 + 16 = 80KB -> 2 blocks/CU. Grid 512 = 2/CU exact.
__global__ __launch_bounds__(256, 2) void attn_kernel(
    const unsigned short* __restrict__ Qw,   // [bh][2048][128]
    const unsigned short* __restrict__ Kw,   // [bh][2048][128]
    const unsigned short* __restrict__ Vw,   // [bh][128][2048]
    unsigned short* __restrict__ Aw) {       // [b][2048][512]
    __shared__ unsigned short Ks[2][64 * 128];  // [s][ch], swizzled
    __shared__ unsigned short Vs[2][128 * 64];  // [c][s],  swizzled
    __shared__ unsigned short Ps[128 * 64];     // [q][s],  swizzled
    // XCD-friendly decode: all t-tiles of a bh share bid%8 -> same L2 stream
    int bid = blockIdx.x;
    int bh = bid & 31;
    int t0 = (bid >> 5) * 128;
    int tid = threadIdx.x, lane = tid & 63, w = tid >> 6;
    int lr = lane >> 4, lc = lane & 15;
    int qrow = w * 32;

    const unsigned short* Kbase = &Kw[(size_t)bh * 2048 * 128];
    const unsigned short* Vbase = &Vw[(size_t)bh * 128 * 2048];

    // Q fragments resident: rows qrow + m*16 + lc, k = kk*32 + lr*8
    short8 qf[2][4];
    for (int m = 0; m < 2; m++)
        for (int kk = 0; kk < 4; kk++)
            qf[m][kk] = *(const short8*)&Qw[((size_t)bh * 2048 + t0 + qrow + m * 16 + lc) * 128 + kk * 32 + lr * 8];

    f32x4 oacc[2][8];
    for (int m = 0; m < 2; m++)
        for (int n = 0; n < 8; n++) oacc[m][n] = (f32x4){0.f, 0.f, 0.f, 0.f};
    float mst[2][4], lst[2][4];
    for (int m = 0; m < 2; m++)
        for (int r = 0; r < 4; r++) { mst[m][r] = -1e30f; lst[m][r] = 0.f; }

    int kr = tid >> 4, ko = (tid & 15) * 8;   // K stage: rows kr+p*16
    int vr = tid >> 3, vo = (tid & 7) * 8;    // V stage: rows vr+p*32

    // prologue: load tile 0 into regs
    short8 kreg[4], vreg[4];
    for (int p = 0; p < 4; p++)
        kreg[p] = *(const short8*)&Kbase[(size_t)(kr + p * 16) * 128 + ko];
    for (int p = 0; p < 4; p++)
        vreg[p] = *(const short8*)&Vbase[(size_t)(vr + p * 32) * 2048 + vo];

    for (int it = 0; it < 32; ++it) {
        int cur = it & 1;
        unsigned short* Kb = &Ks[cur][0];
        unsigned short* Vb = &Vs[cur][0];
        // write staged tile to LDS (waits vmcnt for the year-old loads)
        for (int p = 0; p < 4; p++) *(short8*)swp(Kb, kr + p * 16, ko, 128) = kreg[p];
        for (int p = 0; p < 4; p++) *(short8*)swp(Vb, vr + p * 32, vo, 64) = vreg[p];
        // issue prefetch for tile it+1 (latency hides under this tile's compute)
        if (it + 1 < 32) {
            int s1 = (it + 1) * 64;
            for (int p = 0; p < 4; p++)
                kreg[p] = *(const short8*)&Kbase[(size_t)(s1 + kr + p * 16) * 128 + ko];
            for (int p = 0; p < 4; p++)
                vreg[p] = *(const short8*)&Vbase[(size_t)(vr + p * 32) * 2048 + s1 + vo];
        }
        __syncthreads();  // the ONE barrier per tile

        // S = Q K^T
        f32x4 sacc[2][4];
        for (int m = 0; m < 2; m++)
            for (int n = 0; n < 4; n++) sacc[m][n] = (f32x4){0.f, 0.f, 0.f, 0.f};
        __builtin_amdgcn_s_setprio(1);
        for (int kk = 0; kk < 4; kk++) {
            short8 kf[4];
            for (int n = 0; n < 4; n++)
                kf[n] = *(const short8*)swp(Kb, n * 16 + lc, kk * 32 + lr * 8, 128);
            for (int m = 0; m < 2; m++)
                for (int n = 0; n < 4; n++)
                    sacc[m][n] = __builtin_amdgcn_mfma_f32_16x16x32_bf16(qf[m][kk], kf[n], sacc[m][n], 0, 0, 0);
        }
        __builtin_amdgcn_s_setprio(0);
        // online softmax (rows lr*4+r), 16-lane-group reduce
        for (int m = 0; m < 2; m++)
            for (int r = 0; r < 4; r++) {
                float mx = fmaxf(fmaxf(sacc[m][0][r], sacc[m][1][r]),
                                 fmaxf(sacc[m][2][r], sacc[m][3][r]));
                for (int d = 1; d < 16; d <<= 1) mx = fmaxf(mx, __shfl_xor(mx, d, 64));
                float mnew = fmaxf(mst[m][r], mx);
                float resc = __expf(mst[m][r] - mnew);
                mst[m][r] = mnew;
                float rs = 0.f;
                for (int n = 0; n < 4; n++) {
                    float p0 = __expf(sacc[m][n][r] - mnew);
                    sacc[m][n][r] = p0;
                    rs += p0;
                }
                for (int d = 1; d < 16; d <<= 1) rs += __shfl_xor(rs, d, 64);
                lst[m][r] = lst[m][r] * resc + rs;
                for (int n = 0; n < 8; n++) oacc[m][n][r] *= resc;
            }
        // P -> LDS (bf16), wave-private rows, swizzled
        for (int m = 0; m < 2; m++)
            for (int n = 0; n < 4; n++)
                for (int r = 0; r < 4; r++)
                    *swp(Ps, qrow + m * 16 + lr * 4 + r, n * 16 + lc, 64) = f2bf(sacc[m][n][r]);
        asm volatile("" ::: "memory");
        // O += P V^T
        __builtin_amdgcn_s_setprio(1);
        for (int kk = 0; kk < 2; kk++) {
            short8 pa[2], vb[8];
            for (int m = 0; m < 2; m++)
                pa[m] = *(const short8*)swp(Ps, qrow + m * 16 + lc, kk * 32 + lr * 8, 64);
            for (int n = 0; n < 8; n++)
                vb[n] = *(const short8*)swp(Vb, n * 16 + lc, kk * 32 + lr * 8, 64);
            for (int m = 0; m < 2; m++)
                for (int n = 0; n < 8; n++)
                    oacc[m][n] = __builtin_amdgcn_mfma_f32_16x16x32_bf16(pa[m], vb[n], oacc[m][n], 0, 0, 0);
        }
        __builtin_amdgcn_s_setprio(0);
        // no trailing barrier needed: next iter's LDS writes go to the other
        // buffer, and its barrier orders them against this tile's reads.
    }
    // epilogue: O / l -> Aw[b][t][h*128+c]
    int b = bh >> 2, h = bh & 3;
    for (int m = 0; m < 2; m++) {
        float inv[4];
        for (int r = 0; r < 4; r++) inv[r] = 1.f / lst[m][r];
        for (int n = 0; n < 8; n++)
            for (int r = 0; r < 4; r++) {
                int t = t0 + qrow + m * 16 + lr * 4 + r;
                int c = h * 128 + n * 16 + lc;
                Aw[((size_t)(b * 2048) + t) * 512 + c] = f2bf(oacc[m][n][r] * inv[r]);
            }
    }
}

// ---------------- kernel 4: proj GEMM + bias + residual ----------------
__global__ __launch_bounds__(256, 2) void gemm_proj_kernel(
    const unsigned short* __restrict__ Wp,   // [512][512] bf16
    const unsigned short* __restrict__ Aw,   // [b][2048][512] bf16
    const float* __restrict__ proj_b,
    const float* __restrict__ x,             // [b][512][2048] f32
    float* __restrict__ out) {
    __shared__ unsigned short Ws[128][LP];   // [o][k]
    __shared__ unsigned short Bs[128][LP];   // [t][k]
    int b  = blockIdx.z;
    int o0 = blockIdx.y * 128, t0 = blockIdx.x * 128;
    int tid = threadIdx.x, lane = tid & 63, w = tid >> 6;
    int lr = lane >> 4, lc = lane & 15;
    int wr = (w >> 1) * 64, wc = (w & 1) * 64;
    f32x4 acc[4][4];
    for (int m = 0; m < 4; m++)
        for (int n = 0; n < 4; n++) acc[m][n] = (f32x4){0.f, 0.f, 0.f, 0.f};
    int srow = tid >> 3, soff = (tid & 7) * 8;
    for (int k0 = 0; k0 < 512; k0 += 64) {
        __syncthreads();
        for (int rr = srow; rr < 128; rr += 32) {
            *(short8*)&Ws[rr][soff] = *(const short8*)&Wp[(size_t)(o0 + rr) * 512 + k0 + soff];
            *(short8*)&Bs[rr][soff] = *(const short8*)&Aw[((size_t)(b * 2048) + t0 + rr) * 512 + k0 + soff];
        }
        __syncthreads();
        for (int kk = 0; kk < 64; kk += 32) {
            int kb = kk + lr * 8;
            short8 af[4], bfv[4];
            for (int m = 0; m < 4; m++) af[m]  = *(const short8*)&Ws[wr + m * 16 + lc][kb];
            for (int n = 0; n < 4; n++) bfv[n] = *(const short8*)&Bs[wc + n * 16 + lc][kb];
            for (int m = 0; m < 4; m++)
                for (int n = 0; n < 4; n++)
                    acc[m][n] = __builtin_amdgcn_mfma_f32_16x16x32_bf16(af[m], bfv[n], acc[m][n], 0, 0, 0);
        }
    }
    // D[m=o][n=t]; out = x + h + bias (residual in fp32, exact)
    for (int m = 0; m < 4; m++)
        for (int n = 0; n < 4; n++)
            for (int r = 0; r < 4; r++) {
                int o = o0 + wr + m * 16 + lr * 4 + r;
                int t = t0 + wc + n * 16 + lc;
                size_t idx = ((size_t)(b * 512) + o) * 2048 + t;
                out[idx] = x[idx] + acc[m][n][r] + proj_b[o];
            }
}

extern "C" void kernel_launch(void* const* d_in, const int* in_sizes, int n_in,
                              void* d_out, int out_size, void* d_ws, size_t ws_size,
                              hipStream_t stream) {
    const float* x      = (const float*)d_in[0];
    const float* qkv_w  = (const float*)d_in[1];
    const float* qkv_b  = (const float*)d_in[2];
    const float* proj_w = (const float*)d_in[3];
    const float* proj_b = (const float*)d_in[4];
    float* out = (float*)d_out;

    unsigned short* ws = (unsigned short*)d_ws;
    unsigned short* Wq = ws;                                   // 1536*512
    unsigned short* Wp = Wq + (size_t)1536 * 512;              // 512*512
    unsigned short* Xt = Wp + (size_t)512 * 512;               // 8*2048*512
    unsigned short* Qw = Xt + (size_t)8 * 2048 * 512;          // 32*2048*128
    unsigned short* Kw = Qw + (size_t)32 * 2048 * 128;
    unsigned short* Vw = Kw + (size_t)32 * 2048 * 128;
    unsigned short* Aw = Vw + (size_t)32 * 2048 * 128;         // 8*2048*512

    prep_kernel<<<dim3(512), dim3(256), 0, stream>>>(qkv_w, proj_w, Wq, Wp);
    transpose_kernel<<<dim3(32, 8, 8), dim3(256), 0, stream>>>(x, Xt);
    gemm_qkv_kernel<0><<<dim3(16, 8, 8), dim3(256), 0, stream>>>(Wq, Xt, qkv_b, Qw, Kw, Vw);
    gemm_qkv_kernel<1><<<dim3(16, 4, 8), dim3(256), 0, stream>>>(Wq, Xt, qkv_b, Qw, Kw, Vw);
    attn_kernel<<<dim3(512), dim3(256), 0, stream>>>(Qw, Kw, Vw, Aw);
    gemm_proj_kernel<<<dim3(16, 4, 8), dim3(256), 0, stream>>>(Wp, Aw, proj_b, x, out);
}

// Round 5
// 178.587 us; speedup vs baseline: 1.6321x; 1.5983x over previous
//
#include <hip/hip_runtime.h>

#define DEV static __device__ __forceinline__

typedef __attribute__((ext_vector_type(8))) short short8;
typedef __attribute__((ext_vector_type(4))) float f32x4;
typedef __attribute__((ext_vector_type(16))) float f32x16;

DEV unsigned short f2bf(float f) {
    union { float f; unsigned int u; } v; v.f = f;
    unsigned int u = v.u;
    unsigned int r = (u + 0x7fffu + ((u >> 16) & 1u)) >> 16;
    return (unsigned short)r;
}

// v_cvt_pk_bf16_f32: low short = lo, high short = hi (no builtin on gfx950, m240)
DEV unsigned int cvtpk(float lo, float hi) {
    unsigned int r;
    asm("v_cvt_pk_bf16_f32 %0, %1, %2" : "=v"(r) : "v"(lo), "v"(hi));
    return r;
}

// XOR-swizzled LDS pointer: tile row stride rs shorts (power of 2), byte ^= (row&7)<<4
DEV unsigned short* swp(unsigned short* base, int row, int col, int rs) {
    int a = ((row * rs + col) << 1) ^ ((row & 7) << 4);
    return (unsigned short*)((char*)base + a);
}

// ---------------- kernel 0: fp32 weights -> bf16 ----------------
__global__ void prep_kernel(const float* __restrict__ qkv_w,
                            const float* __restrict__ proj_w,
                            unsigned short* __restrict__ Wq,
                            unsigned short* __restrict__ Wp) {
    int i = blockIdx.x * blockDim.x + threadIdx.x;
    int stride = gridDim.x * blockDim.x;
    for (int j = i; j < 1536 * 512; j += stride) Wq[j] = f2bf(qkv_w[j]);
    for (int j = i; j < 512 * 512;  j += stride) Wp[j] = f2bf(proj_w[j]);
}

// ---------------- kernel 1: x [b][512][2048] f32 -> Xt [b][2048][512] bf16
__global__ __launch_bounds__(256) void transpose_kernel(const float* __restrict__ x,
                                                        unsigned short* __restrict__ Xt) {
    __shared__ unsigned char lt[64 * 128];  // 64 c-rows x 64 t bf16, XOR-swizzled
    int b  = blockIdx.z;
    int c0 = blockIdx.y * 64;
    int t0 = blockIdx.x * 64;
    int tid = threadIdx.x;
    int tx = tid & 15, cy0 = tid >> 4;
    for (int p = 0; p < 4; ++p) {
        int cy = cy0 + p * 16;
        const float* src = &x[((size_t)(b * 512 + c0 + cy)) * 2048 + t0 + tx * 4];
        f32x4 v = *(const f32x4*)src;
        unsigned long long pk = (unsigned long long)f2bf(v[0])
                              | ((unsigned long long)f2bf(v[1]) << 16)
                              | ((unsigned long long)f2bf(v[2]) << 32)
                              | ((unsigned long long)f2bf(v[3]) << 48);
        int addr = (cy * 128 + tx * 8) ^ ((cy & 7) << 4);
        *(unsigned long long*)(lt + addr) = pk;
    }
    __syncthreads();
    int c16 = (tid & 3) * 16, tr = tid >> 2;
    unsigned short buf[16];
    for (int i = 0; i < 16; ++i) {
        int c = c16 + i;
        int addr = (c * 128 + tr * 2) ^ ((c & 7) << 4);
        buf[i] = *(unsigned short*)(lt + addr);
    }
    unsigned short* dst = &Xt[((size_t)(b * 2048 + t0 + tr)) * 512 + c0 + c16];
    *(short8*)dst       = *(short8*)&buf[0];
    *(short8*)(dst + 8) = *(short8*)&buf[8];
}

// ---------------- kernel 2: QKV GEMM ----------------
#define LP 72  // 64 + 8 pad

template <int ORIENT>
__global__ __launch_bounds__(256, 2) void gemm_qkv_kernel(
    const unsigned short* __restrict__ Wq,   // [1536][512] bf16
    const unsigned short* __restrict__ Xt,   // [b][2048][512] bf16
    const float* __restrict__ qkv_b,
    unsigned short* __restrict__ Qw,
    unsigned short* __restrict__ Kw,
    unsigned short* __restrict__ Vw) {
    __shared__ unsigned short Ws[128][LP];   // [o][k]
    __shared__ unsigned short Bs[128][LP];   // [t][k]
    int b  = blockIdx.z;
    int ot = (ORIENT == 0) ? blockIdx.y : (8 + blockIdx.y);
    int o0 = ot * 128, t0 = blockIdx.x * 128;
    int tid = threadIdx.x, lane = tid & 63, w = tid >> 6;
    int lr = lane >> 4, lc = lane & 15;
    int wr = (w >> 1) * 64, wc = (w & 1) * 64;
    f32x4 acc[4][4];
    for (int m = 0; m < 4; m++)
        for (int n = 0; n < 4; n++) acc[m][n] = (f32x4){0.f, 0.f, 0.f, 0.f};
    int srow = tid >> 3, soff = (tid & 7) * 8;
    for (int k0 = 0; k0 < 512; k0 += 64) {
        __syncthreads();
        for (int rr = srow; rr < 128; rr += 32) {
            *(short8*)&Ws[rr][soff] = *(const short8*)&Wq[(size_t)(o0 + rr) * 512 + k0 + soff];
            *(short8*)&Bs[rr][soff] = *(const short8*)&Xt[((size_t)(b * 2048) + t0 + rr) * 512 + k0 + soff];
        }
        __syncthreads();
        for (int kk = 0; kk < 64; kk += 32) {
            int kb = kk + lr * 8;
            short8 af[4], bfv[4];
            if (ORIENT == 0) {
                for (int m = 0; m < 4; m++) af[m]  = *(const short8*)&Bs[wr + m * 16 + lc][kb];
                for (int n = 0; n < 4; n++) bfv[n] = *(const short8*)&Ws[wc + n * 16 + lc][kb];
            } else {
                for (int m = 0; m < 4; m++) af[m]  = *(const short8*)&Ws[wr + m * 16 + lc][kb];
                for (int n = 0; n < 4; n++) bfv[n] = *(const short8*)&Bs[wc + n * 16 + lc][kb];
            }
            for (int m = 0; m < 4; m++)
                for (int n = 0; n < 4; n++)
                    acc[m][n] = __builtin_amdgcn_mfma_f32_16x16x32_bf16(af[m], bfv[n], acc[m][n], 0, 0, 0);
        }
    }
    const float scale = 0.29730177875068026f;  // 128^-0.25
    for (int m = 0; m < 4; m++)
        for (int n = 0; n < 4; n++)
            for (int r = 0; r < 4; r++) {
                int row = wr + m * 16 + lr * 4 + r;
                int col = wc + n * 16 + lc;
                float val = acc[m][n][r];
                if (ORIENT == 0) {
                    int t = t0 + row;
                    int o = o0 + col;
                    val = (val + qkv_b[o]) * scale;
                    if (o < 512) {
                        int h = o >> 7, cc = o & 127;
                        Qw[((size_t)((b * 4 + h) * 2048 + t)) * 128 + cc] = f2bf(val);
                    } else {
                        int oo = o - 512;
                        int h = oo >> 7, cc = oo & 127;
                        Kw[((size_t)((b * 4 + h) * 2048 + t)) * 128 + cc] = f2bf(val);
                    }
                } else {
                    int o = o0 + row;
                    int t = t0 + col;
                    val += qkv_b[o];
                    int oo = o - 1024;
                    int h = oo >> 7, cc = oo & 127;
                    Vw[((size_t)((b * 4 + h) * 128 + cc)) * 2048 + t] = f2bf(val);
                }
            }
}

// ---------------- kernel 3: flash attention v4b (swapped-QK 32x32, P in-register) --
// 512 threads = 8 waves x 32 q-rows = 256 q/block; KV tiles of 64; 256 blocks (1/CU).
// mfma_32x32x16(K,Q): D col=lane&31=q, row=s -> full P-row per lane, softmax in-lane.
// P -> PV B-frags via cvt_pk + half-exchange (T12). Single barrier/tile, reg prefetch.
__global__ __launch_bounds__(512, 2) void attn_kernel(
    const unsigned short* __restrict__ Qw,   // [bh][2048][128]
    const unsigned short* __restrict__ Kw,   // [bh][2048][128]
    const unsigned short* __restrict__ Vw,   // [bh][128][2048]
    unsigned short* __restrict__ Aw) {       // [b][2048][512]
    __shared__ unsigned short lds[32768];    // K dbuf 2x8192, V dbuf 2x8192 shorts
    int bid = blockIdx.x;
    int bh = bid & 31;                       // all t-tiles of a bh share bid%8 (XCD)
    int t0 = (bid >> 5) * 256;
    int tid = threadIdx.x, lane = tid & 63, w = tid >> 6;
    int l31 = lane & 31, hi = lane >> 5;
    int qrow = w * 32;

    const unsigned short* Kbase = &Kw[(size_t)bh * 2048 * 128];
    const unsigned short* Vbase = &Vw[(size_t)bh * 128 * 2048];

    // Q resident as B-frags: Q[q=l31][k = st*16 + hi*8 + 0..7]
    short8 qf[8];
    #pragma unroll
    for (int st = 0; st < 8; st++)
        qf[st] = *(const short8*)&Qw[((size_t)bh * 2048 + t0 + qrow + l31) * 128 + st * 16 + hi * 8];

    f32x16 oacc[4];   // O[c = 32*ct + crow(reg,hi)][q = l31]
    #pragma unroll
    for (int ct = 0; ct < 4; ct++)
        #pragma unroll
        for (int i = 0; i < 16; i++) oacc[ct][i] = 0.f;
    float mst = -1e30f, lst = 0.f;

    int kr = tid >> 4, ko = (tid & 15) * 8;  // K stage rows kr, kr+32
    int vr = tid >> 3, vo = (tid & 7) * 8;   // V stage rows vr, vr+64

    short8 kreg[2], vreg[2];
    #pragma unroll
    for (int p = 0; p < 2; p++)
        kreg[p] = *(const short8*)&Kbase[(size_t)(kr + p * 32) * 128 + ko];
    #pragma unroll
    for (int p = 0; p < 2; p++)
        vreg[p] = *(const short8*)&Vbase[(size_t)(vr + p * 64) * 2048 + vo];

    for (int it = 0; it < 32; ++it) {
        int cur = it & 1;
        unsigned short* Kb = lds + cur * 8192;           // [64 s][128 ch] swz
        unsigned short* Vb = lds + 16384 + cur * 8192;   // [128 c][64 s] swz
        #pragma unroll
        for (int p = 0; p < 2; p++) *(short8*)swp(Kb, kr + p * 32, ko, 128) = kreg[p];
        #pragma unroll
        for (int p = 0; p < 2; p++) *(short8*)swp(Vb, vr + p * 64, vo, 64) = vreg[p];
        if (it + 1 < 32) {
            int s1 = (it + 1) * 64;
            #pragma unroll
            for (int p = 0; p < 2; p++)
                kreg[p] = *(const short8*)&Kbase[(size_t)(s1 + kr + p * 32) * 128 + ko];
            #pragma unroll
            for (int p = 0; p < 2; p++)
                vreg[p] = *(const short8*)&Vbase[(size_t)(vr + p * 64) * 2048 + s1 + vo];
        }
        __syncthreads();

        // S'[s][q] = K·Q^T : A = K rows s, B = Q cols q
        f32x16 s0, s1v;
        #pragma unroll
        for (int i = 0; i < 16; i++) { s0[i] = 0.f; s1v[i] = 0.f; }
        __builtin_amdgcn_s_setprio(1);
        #pragma unroll
        for (int st = 0; st < 8; st++) {
            short8 k0 = *(const short8*)swp(Kb, l31,      st * 16 + hi * 8, 128);
            short8 k1 = *(const short8*)swp(Kb, 32 + l31, st * 16 + hi * 8, 128);
            s0  = __builtin_amdgcn_mfma_f32_32x32x16_bf16(k0, qf[st], s0, 0, 0, 0);
            s1v = __builtin_amdgcn_mfma_f32_32x32x16_bf16(k1, qf[st], s1v, 0, 0, 0);
        }
        __builtin_amdgcn_s_setprio(0);

        // online softmax, fully in-lane (lane owns P-row for q=l31; hi-halves split s)
        float m16[16];
        #pragma unroll
        for (int i = 0; i < 16; i++) m16[i] = fmaxf(s0[i], s1v[i]);
        #pragma unroll
        for (int sdt = 8; sdt > 0; sdt >>= 1)
            #pragma unroll
            for (int i = 0; i < 8; i++)
                if (i < sdt) m16[i] = fmaxf(m16[i], m16[i + sdt]);
        float mx = fmaxf(m16[0], __shfl_xor(m16[0], 32, 64));
        float mnew = fmaxf(mst, mx);
        float resc = __expf(mst - mnew);
        mst = mnew;
        float pe[32];
        #pragma unroll
        for (int i = 0; i < 16; i++) pe[i]      = __expf(s0[i]  - mnew);
        #pragma unroll
        for (int i = 0; i < 16; i++) pe[16 + i] = __expf(s1v[i] - mnew);
        float a16[16];
        #pragma unroll
        for (int i = 0; i < 16; i++) a16[i] = pe[i] + pe[16 + i];
        #pragma unroll
        for (int sdt = 8; sdt > 0; sdt >>= 1)
            #pragma unroll
            for (int i = 0; i < 8; i++)
                if (i < sdt) a16[i] = a16[i] + a16[i + sdt];
        float rs = a16[0] + __shfl_xor(a16[0], 32, 64);
        lst = lst * resc + rs;
        #pragma unroll
        for (int ct = 0; ct < 4; ct++)
            #pragma unroll
            for (int i = 0; i < 16; i++) oacc[ct][i] *= resc;

        // build PV B-frags: frag[st] holds P[s = st*16 + hi*8 + 0..7][q=l31]
        short8 pf[4];
        #pragma unroll
        for (int st = 0; st < 4; st++) {
            unsigned X0 = cvtpk(pe[st * 8 + 0], pe[st * 8 + 1]);
            unsigned X1 = cvtpk(pe[st * 8 + 2], pe[st * 8 + 3]);
            unsigned Y0 = cvtpk(pe[st * 8 + 4], pe[st * 8 + 5]);
            unsigned Y1 = cvtpk(pe[st * 8 + 6], pe[st * 8 + 7]);
            unsigned Xp0 = (unsigned)__shfl_xor((int)X0, 32, 64);
            unsigned Xp1 = (unsigned)__shfl_xor((int)X1, 32, 64);
            unsigned Yp0 = (unsigned)__shfl_xor((int)Y0, 32, 64);
            unsigned Yp1 = (unsigned)__shfl_xor((int)Y1, 32, 64);
            union { unsigned u[4]; short8 s; } uu;
            uu.u[0] = hi ? Yp0 : X0;   // word0: s = base+0,1
            uu.u[1] = hi ? Yp1 : X1;   // word1: s = base+2,3
            uu.u[2] = hi ? Y0  : Xp0;  // word2: s = base+4,5
            uu.u[3] = hi ? Y1  : Xp1;  // word3: s = base+6,7
            pf[st] = uu.s;
        }

        // O[c][q] += V·P : A = V rows c, B = P
        __builtin_amdgcn_s_setprio(1);
        #pragma unroll
        for (int ct = 0; ct < 4; ct++)
            #pragma unroll
            for (int st = 0; st < 4; st++) {
                short8 va = *(const short8*)swp(Vb, ct * 32 + l31, st * 16 + hi * 8, 64);
                oacc[ct] = __builtin_amdgcn_mfma_f32_32x32x16_bf16(va, pf[st], oacc[ct], 0, 0, 0);
            }
        __builtin_amdgcn_s_setprio(0);
    }

    // epilogue: O/l -> per-wave LDS [32 q][128 c] -> coalesced Aw[t][c]
    __syncthreads();
    unsigned short* ep = lds + w * 4096;
    float invl = 1.f / lst;
    #pragma unroll
    for (int ct = 0; ct < 4; ct++)
        #pragma unroll
        for (int i = 0; i < 8; i++) {
            int c = (2 * i & 3) + 8 * (i >> 1) + 4 * hi + 32 * ct;  // crow(2i,hi)
            unsigned d = cvtpk(oacc[ct][2 * i] * invl, oacc[ct][2 * i + 1] * invl);
            *(unsigned*)swp(ep, l31, c, 128) = d;
        }
    asm volatile("" ::: "memory");
    int q = lane >> 1, hf = lane & 1;
    int b = bh >> 2, h = bh & 3;
    #pragma unroll
    for (int p = 0; p < 8; p++) {   // FIX r4: was p<4 stride 16 -> covered only half the cols
        short8 v = *(const short8*)swp(ep, q, hf * 64 + p * 8, 128);
        *(short8*)&Aw[((size_t)(b * 2048) + t0 + qrow + q) * 512 + h * 128 + hf * 64 + p * 8] = v;
    }
}

// ---------------- kernel 4: proj GEMM + bias + residual ----------------
__global__ __launch_bounds__(256, 2) void gemm_proj_kernel(
    const unsigned short* __restrict__ Wp,   // [512][512] bf16
    const unsigned short* __restrict__ Aw,   // [b][2048][512] bf16
    const float* __restrict__ proj_b,
    const float* __restrict__ x,             // [b][512][2048] f32
    float* __restrict__ out) {
    __shared__ unsigned short Ws[128][LP];
    __shared__ unsigned short Bs[128][LP];
    int b  = blockIdx.z;
    int o0 = blockIdx.y * 128, t0 = blockIdx.x * 128;
    int tid = threadIdx.x, lane = tid & 63, w = tid >> 6;
    int lr = lane >> 4, lc = lane & 15;
    int wr = (w >> 1) * 64, wc = (w & 1) * 64;
    f32x4 acc[4][4];
    for (int m = 0; m < 4; m++)
        for (int n = 0; n < 4; n++) acc[m][n] = (f32x4){0.f, 0.f, 0.f, 0.f};
    int srow = tid >> 3, soff = (tid & 7) * 8;
    for (int k0 = 0; k0 < 512; k0 += 64) {
        __syncthreads();
        for (int rr = srow; rr < 128; rr += 32) {
            *(short8*)&Ws[rr][soff] = *(const short8*)&Wp[(size_t)(o0 + rr) * 512 + k0 + soff];
            *(short8*)&Bs[rr][soff] = *(const short8*)&Aw[((size_t)(b * 2048) + t0 + rr) * 512 + k0 + soff];
        }
        __syncthreads();
        for (int kk = 0; kk < 64; kk += 32) {
            int kb = kk + lr * 8;
            short8 af[4], bfv[4];
            for (int m = 0; m < 4; m++) af[m]  = *(const short8*)&Ws[wr + m * 16 + lc][kb];
            for (int n = 0; n < 4; n++) bfv[n] = *(const short8*)&Bs[wc + n * 16 + lc][kb];
            for (int m = 0; m < 4; m++)
                for (int n = 0; n < 4; n++)
                    acc[m][n] = __builtin_amdgcn_mfma_f32_16x16x32_bf16(af[m], bfv[n], acc[m][n], 0, 0, 0);
        }
    }
    for (int m = 0; m < 4; m++)
        for (int n = 0; n < 4; n++)
            for (int r = 0; r < 4; r++) {
                int o = o0 + wr + m * 16 + lr * 4 + r;
                int t = t0 + wc + n * 16 + lc;
                size_t idx = ((size_t)(b * 512) + o) * 2048 + t;
                out[idx] = x[idx] + acc[m][n][r] + proj_b[o];
            }
}

extern "C" void kernel_launch(void* const* d_in, const int* in_sizes, int n_in,
                              void* d_out, int out_size, void* d_ws, size_t ws_size,
                              hipStream_t stream) {
    const float* x      = (const float*)d_in[0];
    const float* qkv_w  = (const float*)d_in[1];
    const float* qkv_b  = (const float*)d_in[2];
    const float* proj_w = (const float*)d_in[3];
    const float* proj_b = (const float*)d_in[4];
    float* out = (float*)d_out;

    unsigned short* ws = (unsigned short*)d_ws;
    unsigned short* Wq = ws;                                   // 1536*512
    unsigned short* Wp = Wq + (size_t)1536 * 512;              // 512*512
    unsigned short* Xt = Wp + (size_t)512 * 512;               // 8*2048*512
    unsigned short* Qw = Xt + (size_t)8 * 2048 * 512;          // 32*2048*128
    unsigned short* Kw = Qw + (size_t)32 * 2048 * 128;
    unsigned short* Vw = Kw + (size_t)32 * 2048 * 128;
    unsigned short* Aw = Vw + (size_t)32 * 2048 * 128;         // 8*2048*512

    prep_kernel<<<dim3(512), dim3(256), 0, stream>>>(qkv_w, proj_w, Wq, Wp);
    transpose_kernel<<<dim3(32, 8, 8), dim3(256), 0, stream>>>(x, Xt);
    gemm_qkv_kernel<0><<<dim3(16, 8, 8), dim3(256), 0, stream>>>(Wq, Xt, qkv_b, Qw, Kw, Vw);
    gemm_qkv_kernel<1><<<dim3(16, 4, 8), dim3(256), 0, stream>>>(Wq, Xt, qkv_b, Qw, Kw, Vw);
    attn_kernel<<<dim3(256), dim3(512), 0, stream>>>(Qw, Kw, Vw, Aw);
    gemm_proj_kernel<<<dim3(16, 4, 8), dim3(256), 0, stream>>>(Wp, Aw, proj_b, x, out);
}